// Round 1
// baseline (368.934 us; speedup 1.0000x reference)
//
#include <hip/hip_runtime.h>
#include <hip/hip_bf16.h>
#include <stdint.h>

typedef __attribute__((ext_vector_type(4))) float fx4;
typedef __attribute__((ext_vector_type(8))) short bf8;   // 8 bf16 in 4 VGPRs

#define KDIM  784
#define KPAD  832    // Gb row stride (13*64) -- layout unchanged
#define NROW  256    // padded output columns (234 real)
#define BM    64
#define BK    32
#define NT    25     // K-tiles of 32 actually computed: k 0..799 (Gb==0 for k>=784)

static __device__ __forceinline__ unsigned short f2bf(float f) {
  union { float f; uint32_t u; } v; v.f = f;
  uint32_t u = v.u;
  u += 0x7FFFu + ((u >> 16) & 1u);   // round-to-nearest-even
  return (unsigned short)(u >> 16);
}

// 20-step scalar recurrence coefficients (uniform, recomputed per block — cheap)
struct Coefs { float a,p,q,r,tt,w,m,n,o,g,h; };
static __device__ __forceinline__ Coefs pc_coefs(float l1, float l2, float l3) {
  float lam1 = 0.8f + 0.2f * l1;
  float lam2 = 0.8f + 0.2f * l2;
  float lam3 = 0.8f + 0.2f * l3;
  Coefs c{0,0,0,0,0,0,0,0,0,0,1};
  for (int i = 0; i < 20; ++i) {
    float a2 = lam1*c.a + 0.2f;
    float p2 = lam2*c.p + 0.2f*c.a, q2 = lam2*c.q + 0.2f;
    float r2 = lam3*c.r + 0.2f*c.p, t2 = lam3*c.tt + 0.2f*c.q, w2 = lam3*c.w + 0.2f;
    float m2 = 0.8f*c.m + 0.2f*c.r, n2 = 0.8f*c.n + 0.2f*c.tt, o2 = 0.8f*c.o + 0.2f*c.w;
    float g2 = 0.8f*c.g + 0.2f,     h2 = 0.8f*c.h;
    c.a=a2; c.p=p2; c.q=q2; c.r=r2; c.tt=t2; c.w=w2; c.m=m2; c.n=n2; c.o=o2; c.g=g2; c.h=h2;
  }
  return c;
}

// ---------------- single prep kernel: 257 independent blocks -------------------
// blocks 0..255: Gb row nrow  (bf16, pre-scaled, K zero-padded to 832)
// block  256   : dvec[256]
__global__ void pc_prep(const float* __restrict__ W1, const float* __restrict__ W2,
                        const float* __restrict__ W3, const float* __restrict__ W4,
                        const float* __restrict__ L1, const float* __restrict__ L2,
                        const float* __restrict__ L3,
                        const float* __restrict__ b1, const float* __restrict__ b2,
                        const float* __restrict__ b3, const float* __restrict__ b4,
                        unsigned short* __restrict__ Gb, float* __restrict__ dvec)
{
  __shared__ float sr[128];     // combining row over W1 rows
  __shared__ float saux[64];    // W43 row  (or W2@b1 in dvec block)
  const int t = threadIdx.x;
  const int nrow = blockIdx.x;
  const Coefs C = pc_coefs(L1[0], L2[0], L3[0]);

  if (nrow == 256) {
    // ---- dvec ----
    __shared__ float sW43[10*64];
    if (t < 64) {                               // saux = W2 @ b1  [64]
      float s = 0.f;
      for (int j = 0; j < 128; ++j) s += W2[t*128+j] * b1[j];
      saux[t] = s;
    }
    for (int e = t; e < 10*64; e += 256) {      // W43 = W4@W3 [10,64]
      int i = e >> 6, k = e & 63;
      float s = 0.f;
      for (int j = 0; j < 32; ++j) s += W4[i*32+j] * W3[j*64+k];
      sW43[e] = s;
    }
    __syncthreads();
    float v = 0.f;
    int c = t;
    if (c < 128) v = C.a * b1[c];
    else if (c < 192) { int i = c-128; v = C.p*saux[i] + C.q*b2[i]; }
    else if (c < 224) { int i = c-192;
      float u1 = 0.f, u2 = 0.f;
      for (int j = 0; j < 64; ++j) { float w3 = W3[i*64+j]; u1 += w3*saux[j]; u2 += w3*b2[j]; }
      v = C.r*u1 + C.tt*u2 + C.w*b3[i];
    } else if (c < 234) { int i = c-224;
      float u1 = 0.f, u2 = 0.f, u3 = 0.f;
      for (int j = 0; j < 64; ++j) { float w43 = sW43[i*64+j]; u1 += w43*saux[j]; u2 += w43*b2[j]; }
      for (int j = 0; j < 32; ++j) u3 += W4[i*32+j] * b3[j];
      v = C.m*u1 + C.n*u2 + C.o*u3 + C.g*b4[i] + C.h*0.1f;
    }
    dvec[c] = v;
    return;
  }

  // ---- Gb row nrow: coef * (comb @ W1)  where comb depends on the segment ----
  float coef = 0.f;
  bool  direct = false;
  if (nrow < 128)      { coef = C.a; direct = true; }
  else if (nrow < 192) { coef = C.p;
    if (t < 128) sr[t] = W2[(nrow-128)*128 + t];
  }
  else if (nrow < 224) { coef = C.r;                 // row of W3@W2
    int i = nrow - 192;
    if (t < 128) {
      float s = 0.f;
      for (int j = 0; j < 64; ++j) s += W3[i*64+j] * W2[j*128+t];
      sr[t] = s;
    }
  }
  else if (nrow < 234) { coef = C.m;                 // row of (W4@W3)@W2
    int i = nrow - 224;
    if (t < 64) {
      float s = 0.f;
      for (int j = 0; j < 32; ++j) s += W4[i*32+j] * W3[j*64+t];
      saux[t] = s;
    }
    __syncthreads();
    if (t < 128) {
      float s = 0.f;
      for (int j = 0; j < 64; ++j) s += saux[j] * W2[j*128+t];
      sr[t] = s;
    }
  }
  __syncthreads();
  for (int k = t; k < KPAD; k += 256) {
    float v = 0.f;
    if (k < KDIM && nrow < 234) {
      if (direct) v = coef * W1[nrow*KDIM + k];
      else {
        float s = 0.f;
        #pragma unroll 8
        for (int j = 0; j < 128; ++j) s += sr[j] * W1[j*KDIM + k];
        v = coef * s;
      }
    }
    Gb[nrow*KPAD + k] = f2bf(v);
  }
}

// ---------------- main GEMM: out = x @ Gb^T + d, routed into s1..s4 ------------
// T3-min 2-phase pipeline: BK=32, double-buffered xs/gs (LDS 40 KB -> 4 blk/CU),
// stage tile t+1 during compute of tile t, counted s_waitcnt vmcnt(2) (never 0
// in the loop), one bare s_barrier per iteration. The only ops crossing the
// barrier are the 2 x HBM register-prefetch loads.
// 16B-chunk XOR swizzle within 4-chunk rows: chunk c of row r at slot r*4+(c^(r&3)).
#define GLDS16(gp, lp) __builtin_amdgcn_global_load_lds(                          \
    (const __attribute__((address_space(1))) void*)(gp),                          \
    (__attribute__((address_space(3))) void*)(lp), 16, 0, 0)

__global__ __launch_bounds__(256, 4)
void pc_main(const float* __restrict__ x, const unsigned short* __restrict__ Gb,
             const float* __restrict__ dvec, float* __restrict__ out)
{
  __shared__ __align__(16) unsigned short xs[2][BM*BK];    // 2 x 4 KB
  __shared__ __align__(16) unsigned short gs[2][NROW*BK];  // 2 x 16 KB
  const int tid  = threadIdx.x;
  const int lane = tid & 63;
  const int w    = tid >> 6;            // 0..3: each wave owns 64 cols x 64 rows
  const int quad = lane >> 4, l16 = lane & 15;
  const size_t row0 = (size_t)blockIdx.x * BM;

  // x staging: thread owns row xr = tid>>2, segment xseg = tid&3 (8 floats)
  const int xr = tid >> 2, xseg = tid & 3;
  const float* xsrc = x + (row0 + (size_t)xr) * KDIM + xseg * 8;
  const int xoff = (xr*4 + (xseg ^ (xr & 3))) * 8;   // shorts offset of 16B slot

  // G staging: 4 GLDS16/wave/tile; dest slot s = w*256 + i*64 + lane
  // n = s>>2 = w*64 + i*16 + (lane>>2); pos = lane&3; src chunk = pos ^ (n&3)
  const unsigned short* gsrc[4];
  {
    const int n_lane = lane >> 2;
    const int c_lane = (lane & 3) ^ (n_lane & 3);
    #pragma unroll
    for (int i = 0; i < 4; ++i)
      gsrc[i] = Gb + (size_t)(w*64 + i*16 + n_lane) * KPAD + c_lane * 8;
  }

  fx4 xv0, xv1;

  fx4 acc[4][4];
  #pragma unroll
  for (int i = 0; i < 4; ++i)
    #pragma unroll
    for (int j = 0; j < 4; ++j) acc[i][j] = (fx4){0.f,0.f,0.f,0.f};

  auto stageG = [&](int kb, int buf) {
    unsigned short* gb = &gs[buf][w*2048];
    #pragma unroll
    for (int i = 0; i < 4; ++i) GLDS16(gsrc[i] + kb*BK, gb + i*512);
  };
  // Always issues exactly 2 wave-uniform loads (vmcnt-count uniform). For the
  // K tail the address is clamped to tile 0: garbage (finite) x values multiply
  // Gb's zero padding -> exact 0 contribution, numerics unchanged.
  auto loadx = [&](int kb) {
    const int gk = kb*BK + xseg*8;
    const fx4* sp = (const fx4*)(xsrc + (gk < KDIM ? kb*BK : 0));
    xv0 = sp[0]; xv1 = sp[1];
  };
  auto cvtwrite = [&](int buf) {
    bf8 h;
    #pragma unroll
    for (int j = 0; j < 4; ++j) {
      h[j]   = (short)f2bf(xv0[j]);
      h[4+j] = (short)f2bf(xv1[j]);
    }
    *(bf8*)(&xs[buf][xoff]) = h;
  };
  auto compute = [&](int buf) {
    const bf8* xsv = (const bf8*)&xs[buf][0];
    const bf8* gsv = (const bf8*)&gs[buf][0];
    bf8 bfr[4];
    #pragma unroll
    for (int ct = 0; ct < 4; ++ct) {
      const int nn = w*64 + ct*16 + l16;
      bfr[ct] = gsv[nn*4 + (quad ^ (nn & 3))];
    }
    #pragma unroll
    for (int rt = 0; rt < 4; ++rt) {
      const int rr = rt*16 + l16;
      const bf8 af = xsv[rr*4 + (quad ^ (rr & 3))];
      #pragma unroll
      for (int ct = 0; ct < 4; ++ct)
        acc[rt][ct] = __builtin_amdgcn_mfma_f32_16x16x32_bf16(af, bfr[ct], acc[rt][ct], 0, 0, 0);
    }
  };

  // ---- prologue: stage tile 0, prefetch x(1) regs ----
  // issue order (pinned): x(0) loads [oldest], 4 glds G(0), then x(1) loads.
  loadx(0);
  stageG(0, 0);
  __builtin_amdgcn_sched_barrier(0);
  cvtwrite(0);                       // compiler auto-waits the x(0) loads only
  loadx(1);
  __builtin_amdgcn_sched_barrier(0);
  asm volatile("s_waitcnt vmcnt(2) lgkmcnt(0)" ::: "memory");  // G(0)+xs write done
  __builtin_amdgcn_sched_barrier(0);
  __builtin_amdgcn_s_barrier();
  __builtin_amdgcn_sched_barrier(0);

  // ---- main loop: invariant entering iter t: only x(t+1) (2 loads) in flight --
  #pragma unroll 2
  for (int t = 0; t < NT-1; ++t) {
    const int p = t & 1, q = p ^ 1;
    stageG(t+1, q);                  // 4 glds -> other buffer
    __builtin_amdgcn_sched_barrier(0);   // pin: glds issued before x loads below
    cvtwrite(q);                     // xv = x(t+1); auto-wait leaves glds flying
    loadx(t+2);                      // 2 HBM loads; cross the barrier in flight
    compute(p);                      // 8 ds_read_b128 + 16 MFMA on current tile
    __builtin_amdgcn_sched_barrier(0);
    asm volatile("s_waitcnt vmcnt(2) lgkmcnt(0)" ::: "memory");  // G(t+1) done,
    __builtin_amdgcn_sched_barrier(0);                           // x(t+2) NOT drained
    __builtin_amdgcn_s_barrier();
    __builtin_amdgcn_sched_barrier(0);
  }
  compute((NT-1) & 1);               // tile 24 (k 768..799); tile 25 is all-zero G

  // epilogue: add d, route columns into s1/s2/s3/s4 regions
  const size_t O2v = (size_t)65536*128;
  const size_t O3v = O2v + (size_t)65536*64;
  const size_t O4v = O3v + (size_t)65536*32;
  #pragma unroll
  for (int ct = 0; ct < 4; ++ct) {
    int c = w*64 + ct*16 + l16;
    if (c >= 234) continue;            // padding columns
    float dv = dvec[c];
    float* p; int stride;
    if (c < 128)      { p = out + c;             stride = 128; }
    else if (c < 192) { p = out + O2v + (c-128); stride = 64;  }
    else if (c < 224) { p = out + O3v + (c-192); stride = 32;  }
    else              { p = out + O4v + (c-224); stride = 10;  }
    size_t rb = row0 + quad*4;
    #pragma unroll
    for (int rt = 0; rt < 4; ++rt) {
      #pragma unroll
      for (int j = 0; j < 4; ++j) {
        __builtin_nontemporal_store(acc[rt][ct][j] + dv,
                                    p + (rb + rt*16 + j) * (size_t)stride);
      }
    }
  }
}

extern "C" void kernel_launch(void* const* d_in, const int* in_sizes, int n_in,
                              void* d_out, int out_size, void* d_ws, size_t ws_size,
                              hipStream_t stream)
{
  const float* x  = (const float*)d_in[0];
  const float* W1 = (const float*)d_in[1];
  const float* W2 = (const float*)d_in[2];
  const float* W3 = (const float*)d_in[3];
  const float* W4 = (const float*)d_in[4];
  const float* L1 = (const float*)d_in[5];
  const float* L2 = (const float*)d_in[6];
  const float* L3 = (const float*)d_in[7];
  const float* b1 = (const float*)d_in[8];
  const float* b2 = (const float*)d_in[9];
  const float* b3 = (const float*)d_in[10];
  const float* b4 = (const float*)d_in[11];

  char* ws = (char*)d_ws;
  unsigned short* Gb = (unsigned short*)ws;        // 256*832*2 = 425984 B
  float* dvec  = (float*)(ws + 425984);            // 1024 B

  pc_prep<<<257, 256, 0, stream>>>(W1, W2, W3, W4, L1, L2, L3,
                                   b1, b2, b3, b4, Gb, dvec);
  pc_main<<<1024, 256, 0, stream>>>(x, Gb, dvec, (float*)d_out);
}